// Round 7
// baseline (173.068 us; speedup 1.0000x reference)
//
#include <hip/hip_runtime.h>

// AntModel == composed routing: out[b, dest3[dest2[dest1[s]]]] += x[b,s],
// dest_k[s] = argmax_j Wk[s,j] (first max).
//
// R6 -> R7: R6's filter idea was right but K1's grid shorted W3 (it has
// 4096 rows, not 1024) -> poison in dest3. Fixed grid: 12288 waves.
// Established law: time = bytes / ~2.8 TB/s (cold-read service ceiling,
// pattern-independent). Byte reduction: W2 rows read only if reachable
// from dest1 (~63% of 4096) -> ~40 MB instead of 64 MB.
// K1: argmax W1 half-rows (u64 atomicMax) + W3 full rows.   80 MB
// K2: reach2[dest1[s]] = 1.                                  tiny
// K3: argmax W2 half-rows where reach2[row] != 0.           ~40 MB
// K4: compose, K5: per-batch LDS histogram scatter.

#define N_IN   4096
#define N_MID  4096
#define N_OUT  1024
#define BATCH  256

using u32 = unsigned int;
using u64 = unsigned long long;

// order-preserving float->u32: a<b <=> forder(a)<forder(b); always != 0
__device__ __forceinline__ u32 forder(float f) {
    u32 b = __float_as_uint(f);
    return (b & 0x80000000u) ? ~b : (b | 0x80000000u);
}

__device__ __forceinline__ void upd(float v, int idx, float& bv, int& bi) {
    if (v > bv) { bv = v; bi = idx; }   // per-lane idx strictly increases
}

__device__ __forceinline__ void wave_reduce(float& bv, int& bi) {
    #pragma unroll
    for (int off = 1; off < 64; off <<= 1) {
        float ov = __shfl_xor(bv, off, 64);
        int   oi = __shfl_xor(bi, off, 64);
        if (ov > bv || (ov == bv && oi < bi)) { bv = ov; bi = oi; }
    }
}

// 8KB half-row argmax -> packed (forder(v), ~idx) atomicMax
__device__ __forceinline__ void half_row_argmax(const float* __restrict__ W,
                                                int row, int half, int lane,
                                                u64* __restrict__ pk) {
    const float4* __restrict__ p = reinterpret_cast<const float4*>(
        W + (size_t)row * N_MID + half * 2048);
    float4 v[8];
    #pragma unroll
    for (int t = 0; t < 8; ++t) v[t] = p[t * 64 + lane];
    float bv = -__builtin_huge_valf(); int bi = 0;
    #pragma unroll
    for (int t = 0; t < 8; ++t) {
        const int c = half * 2048 + t * 256 + lane * 4;
        upd(v[t].x, c + 0, bv, bi);
        upd(v[t].y, c + 1, bv, bi);
        upd(v[t].z, c + 2, bv, bi);
        upd(v[t].w, c + 3, bv, bi);
    }
    wave_reduce(bv, bi);
    if (lane == 0) {
        u64 key = ((u64)forder(bv) << 32) | (u32)(~(u32)bi);
        atomicMax(&pk[row], key);
    }
}

// K1: W1 half-rows (8192 waves) + W3 full rows (4096 waves of 4KB)
__global__ __launch_bounds__(256) void argmax_w1w3_kernel(
    const float* __restrict__ W1, const float* __restrict__ W3,
    u64* __restrict__ p1, int* __restrict__ dest3) {
    const int g    = (blockIdx.x * 256 + (int)threadIdx.x) >> 6;  // 0..12287
    const int lane = threadIdx.x & 63;
    if (g < 2 * N_IN) {
        half_row_argmax(W1, g >> 1, g & 1, lane, p1);
    } else {
        const int r = g - 2 * N_IN;          // 0..4095 (W3 has N_MID rows)
        const float4* __restrict__ p =
            reinterpret_cast<const float4*>(W3 + (size_t)r * N_OUT);
        float4 v[4];
        #pragma unroll
        for (int t = 0; t < 4; ++t) v[t] = p[t * 64 + lane];
        float bv = -__builtin_huge_valf(); int bi = 0;
        #pragma unroll
        for (int t = 0; t < 4; ++t) {
            const int c = t * 256 + lane * 4;
            upd(v[t].x, c + 0, bv, bi);
            upd(v[t].y, c + 1, bv, bi);
            upd(v[t].z, c + 2, bv, bi);
            upd(v[t].w, c + 3, bv, bi);
        }
        wave_reduce(bv, bi);
        if (lane == 0) dest3[r] = bi;
    }
}

// K2: mark reachable mid neurons
__global__ __launch_bounds__(256) void reach_kernel(
    const u64* __restrict__ p1, int* __restrict__ reach2) {
    const int s = blockIdx.x * 256 + threadIdx.x;
    if (s < N_IN) {
        int d1 = (int)(~(u32)p1[s]) & (N_MID - 1);
        reach2[d1] = 1;   // benign race
    }
}

// K3: W2 half-rows, only reachable rows
__global__ __launch_bounds__(256) void argmax_w2_kernel(
    const float* __restrict__ W2, const int* __restrict__ reach2,
    u64* __restrict__ p2) {
    const int g    = (blockIdx.x * 256 + (int)threadIdx.x) >> 6;  // 0..8191
    const int lane = threadIdx.x & 63;
    const int row  = g >> 1;
    if (reach2[row] == 0) return;   // wave-uniform branch
    half_row_argmax(W2, row, g & 1, lane, p2);
}

__global__ __launch_bounds__(256) void compose_kernel(
    const u64* __restrict__ p1, const u64* __restrict__ p2,
    const int* __restrict__ dest3, int* __restrict__ fdest) {
    const int s = blockIdx.x * blockDim.x + threadIdx.x;
    if (s < N_IN) {
        int d1 = (int)(~(u32)p1[s]) & (N_MID - 1);
        int d2 = (int)(~(u32)p2[d1]) & (N_MID - 1);
        fdest[s] = dest3[d2];
    }
}

__global__ __launch_bounds__(256) void scatter_kernel(
    const int* __restrict__ x, const int* __restrict__ fdest,
    float* __restrict__ out) {
    __shared__ int cnt[N_OUT];
    const int b = blockIdx.x;
    for (int i = threadIdx.x; i < N_OUT; i += 256) cnt[i] = 0;
    __syncthreads();
    const int4* __restrict__ x4 =
        reinterpret_cast<const int4*>(x + (size_t)b * N_IN);
    const int4* __restrict__ f4 = reinterpret_cast<const int4*>(fdest);
    for (int q = threadIdx.x; q < N_IN / 4; q += 256) {
        int4 v = x4[q];
        int4 d = f4[q];
        atomicAdd(&cnt[d.x], v.x);
        atomicAdd(&cnt[d.y], v.y);
        atomicAdd(&cnt[d.z], v.z);
        atomicAdd(&cnt[d.w], v.w);
    }
    __syncthreads();
    float* __restrict__ ob = out + (size_t)b * N_OUT;
    for (int i = threadIdx.x; i < N_OUT; i += 256) ob[i] = (float)cnt[i];
}

extern "C" void kernel_launch(void* const* d_in, const int* in_sizes, int n_in,
                              void* d_out, int out_size, void* d_ws, size_t ws_size,
                              hipStream_t stream) {
    const int*   x  = (const int*)d_in[0];
    const float* W1 = (const float*)d_in[1];
    const float* W2 = (const float*)d_in[2];
    const float* W3 = (const float*)d_in[3];
    float* out = (float*)d_out;

    u64* p1     = (u64*)d_ws;               // [4096] u64
    u64* p2     = p1 + N_IN;                // [4096] u64
    int* reach2 = (int*)(p2 + N_MID);       // [4096] int
    int* dest3  = reach2 + N_MID;           // [4096] int
    int* fdest  = dest3 + N_MID;            // [4096] int

    // zero p1, p2, reach2 (keys always nonzero -> 0 is a valid floor)
    hipMemsetAsync(p1, 0, 2 * N_IN * sizeof(u64) + N_MID * sizeof(int),
                   stream);

    // 8192 W1 half-row waves + 4096 W3 row waves = 12288 waves = 3072 blocks
    argmax_w1w3_kernel<<<(2 * N_IN + N_MID) / 4, 256, 0, stream>>>(
        W1, W3, p1, dest3);
    reach_kernel<<<N_IN / 256, 256, 0, stream>>>(p1, reach2);
    argmax_w2_kernel<<<(2 * N_MID) / 4, 256, 0, stream>>>(W2, reach2, p2);
    compose_kernel<<<N_IN / 256, 256, 0, stream>>>(p1, p2, dest3, fdest);
    scatter_kernel<<<BATCH, 256, 0, stream>>>(x, fdest, out);
}